// Round 1
// baseline (631.547 us; speedup 1.0000x reference)
//
#include <hip/hip_runtime.h>

#define SEQK 512
#define NH 16
#define HD 64
#define RD 1024
#define BBATCH 32
#define MTOT (BBATCH * SEQK)   // 16384
#define QK_SCALE 0.125f        // 1/sqrt(64)

typedef unsigned short u16;
using bf16x8 = __attribute__((ext_vector_type(8))) short;
using f32x4  = __attribute__((ext_vector_type(4))) float;

__device__ __forceinline__ u16 f2bf(float f) {
  unsigned u = __float_as_uint(f);
  u += 0x7FFFu + ((u >> 16) & 1u);   // round-to-nearest-even
  return (u16)(u >> 16);
}

// async global->LDS, 16B per lane. LDS dest must be wave-uniform; HW writes
// lane l's 16B at (base + l*16).
__device__ __forceinline__ void async_cp16(const void* g, void* l) {
  __builtin_amdgcn_global_load_lds(
      (__attribute__((address_space(1))) void*)(void*)g,
      (__attribute__((address_space(3))) void*)l,
      16, 0, 0);
}

// ---------------------------------------------------------------- convert
// h_R (16M) + W_q/W_k/W_v/W_o (4 x 1M) fp32 -> bf16
__global__ void convert_kernel(const float* __restrict__ hR,
                               const float* __restrict__ Wq, const float* __restrict__ Wk,
                               const float* __restrict__ Wv, const float* __restrict__ Wo,
                               u16* __restrict__ hR16,
                               u16* __restrict__ Wq16, u16* __restrict__ Wk16,
                               u16* __restrict__ Wv16, u16* __restrict__ Wo16) {
  size_t i4 = (size_t)blockIdx.x * blockDim.x + threadIdx.x;
  size_t e = i4 * 4;
  const float* src; u16* dst; size_t off;
  if (e < 16777216u) { src = hR; dst = hR16; off = e; }
  else {
    size_t r = e - 16777216u;
    int w = (int)(r >> 20);
    off = r & 1048575u;
    src = (w == 0 ? Wq : w == 1 ? Wk : w == 2 ? Wv : Wo);
    dst = (w == 0 ? Wq16 : w == 1 ? Wk16 : w == 2 ? Wv16 : Wo16);
  }
  float4 v = *(const float4*)(src + off);
  ushort4 o;
  o.x = f2bf(v.x); o.y = f2bf(v.y); o.z = f2bf(v.z); o.w = f2bf(v.w);
  *(ushort4*)(dst + off) = o;
}

// ---------------------------------------------------------------- R normalize
__global__ void rnorm_kernel(const float* __restrict__ R, float* __restrict__ Rn) {
  int row = blockIdx.x;        // 512 rows
  int lane = threadIdx.x;      // 64 threads
  float4 v = *(const float4*)(R + (size_t)row * 256 + lane * 4);
  float ss = v.x * v.x + v.y * v.y + v.z * v.z + v.w * v.w;
  for (int off = 32; off; off >>= 1) ss += __shfl_xor(ss, off);
  float s = 1.0f / fmaxf(sqrtf(ss), 1e-12f);
  float4 o = {v.x * s, v.y * s, v.z * s, v.w * s};
  *(float4*)(Rn + (size_t)row * 256 + lane * 4) = o;
}

// ---------------------------------------------------------------- sim = Rn @ Rn^T
__global__ void sim_kernel(const float* __restrict__ Rn, float* __restrict__ sim) {
  __shared__ float Rl[16 * 256];
  int i0 = blockIdx.x * 16;    // 32 blocks
  int t = threadIdx.x;         // 256 threads
  #pragma unroll
  for (int i = 0; i < 4; i++) {
    int f = t + i * 256;
    *(float4*)&Rl[f * 4] = *(const float4*)(Rn + (size_t)i0 * 256 + f * 4);
  }
  __syncthreads();
  for (int jj = 0; jj < 2; jj++) {
    int j = jj * 256 + t;
    float acc[16];
    #pragma unroll
    for (int i = 0; i < 16; i++) acc[i] = 0.f;
    for (int c = 0; c < 64; c++) {
      float4 rv = *(const float4*)(Rn + (size_t)j * 256 + c * 4);
      #pragma unroll
      for (int i = 0; i < 16; i++) {
        float4 a = *(const float4*)&Rl[i * 256 + c * 4];
        acc[i] += a.x * rv.x + a.y * rv.y + a.z * rv.z + a.w * rv.w;
      }
    }
    #pragma unroll
    for (int i = 0; i < 16; i++) sim[(size_t)(i0 + i) * 512 + j] = acc[i];
  }
}

// ---------------------------------------------------------------- GEMM (bf16 MFMA)
// C[M x N] = A[M x K=1024] @ W^T, W stored [N][K] row-major (torch Linear).
// 128x128 tile per 256-thread block, 4 waves in 2x2, 16x16x32 bf16 MFMA.
// LDS tiles [128][32] bf16 staged via global_load_lds(16B); 16B chunks are
// XOR-swizzled per row (f(r)=(r>>1)&3) so ds_read_b128 fragments are only
// 2-way bank conflicted (free) instead of 8-way.
// MODE 0: fused QKV (blockIdx.y selects Wq/Wk/Wv slice), bf16 out to
//         q/k/v in [B,H,K,D] layout, q pre-scaled by 1/8.
// MODE 1: output proj, fp32 out row-major [M][1024].
template <int MODE>
__global__ __launch_bounds__(256)
void gemm_kernel(const u16* __restrict__ A,
                 const u16* __restrict__ B0, const u16* __restrict__ B1,
                 const u16* __restrict__ B2,
                 u16* __restrict__ q16, u16* __restrict__ k16, u16* __restrict__ v16,
                 float* __restrict__ outF) {
  __shared__ u16 Alds[128 * 32];
  __shared__ u16 Blds[128 * 32];
  int tid = threadIdx.x;
  int wave = tid >> 6, lane = tid & 63;
  int wm = wave & 1, wn = wave >> 1;
  int lr = lane & 15, qd = lane >> 4;
  int mb = blockIdx.x * 128;
  int ny = blockIdx.y;

  const u16* Bmat;
  int nbmat;   // row offset within selected weight matrix
  if (MODE == 0) {
    int wsel = ny >> 3;
    Bmat = (wsel == 0 ? B0 : wsel == 1 ? B1 : B2);
    nbmat = (ny & 7) * 128;
  } else {
    Bmat = B0;
    nbmat = ny * 128;
  }

  f32x4 zero = {0.f, 0.f, 0.f, 0.f};
  f32x4 acc[4][4];
  #pragma unroll
  for (int i = 0; i < 4; i++)
    #pragma unroll
    for (int j = 0; j < 4; j++) acc[i][j] = zero;

  for (int kb = 0; kb < 1024; kb += 32) {
    #pragma unroll
    for (int j = 0; j < 2; j++) {
      int r = (wave * 2 + j) * 16 + (lane >> 2);          // tile row 0..127
      int c = (lane & 3) ^ ((r >> 1) & 3);                 // swizzled 8-elem chunk
      async_cp16(A + (size_t)(mb + r) * 1024 + kb + c * 8,
                 &Alds[(wave * 2 + j) * 512]);
      async_cp16(Bmat + (size_t)(nbmat + r) * 1024 + kb + c * 8,
                 &Blds[(wave * 2 + j) * 512]);
    }
    __syncthreads();   // includes vmcnt(0) drain of global_load_lds

    bf16x8 af[4], bf[4];
    #pragma unroll
    for (int mi = 0; mi < 4; mi++) {
      int ra = wm * 64 + mi * 16 + lr;
      af[mi] = *(const bf16x8*)&Alds[ra * 32 + ((qd ^ ((ra >> 1) & 3)) << 3)];
      int rb = wn * 64 + mi * 16 + lr;
      bf[mi] = *(const bf16x8*)&Blds[rb * 32 + ((qd ^ ((rb >> 1) & 3)) << 3)];
    }
    #pragma unroll
    for (int mi = 0; mi < 4; mi++)
      #pragma unroll
      for (int ni = 0; ni < 4; ni++)
        acc[mi][ni] = __builtin_amdgcn_mfma_f32_16x16x32_bf16(af[mi], bf[ni],
                                                              acc[mi][ni], 0, 0, 0);
    __syncthreads();
  }

  // C layout per 16x16 tile: col = lane&15, row = (lane>>4)*4 + reg
  if (MODE == 0) {
    int wsel = ny >> 3;
    u16* dst = (wsel == 0 ? q16 : wsel == 1 ? k16 : v16);
    float scl = (wsel == 0) ? QK_SCALE : 1.0f;
    #pragma unroll
    for (int mi = 0; mi < 4; mi++) {
      int m = mb + wm * 64 + mi * 16 + qd * 4;   // rows m..m+3
      int b = m >> 9, kk = m & 511;
      #pragma unroll
      for (int ni = 0; ni < 4; ni++) {
        int n = nbmat + wn * 64 + ni * 16 + lr;  // 0..1023 in selected matrix
        int h = n >> 6, d = n & 63;
        u16* p = dst + ((size_t)(b * 16 + h) * 512 + kk) * 64 + d;
        #pragma unroll
        for (int r = 0; r < 4; r++) p[(size_t)r * 64] = f2bf(acc[mi][ni][r] * scl);
      }
    }
  } else {
    #pragma unroll
    for (int mi = 0; mi < 4; mi++) {
      int m = mb + wm * 64 + mi * 16 + qd * 4;
      #pragma unroll
      for (int ni = 0; ni < 4; ni++) {
        int n = ny * 128 + wn * 64 + ni * 16 + lr;
        #pragma unroll
        for (int r = 0; r < 4; r++) outF[(size_t)(m + r) * 1024 + n] = acc[mi][ni][r];
      }
    }
  }
}

// ---------------------------------------------------------------- V transpose
// v16 [BH][K=512][D=64] -> vt16 [BH][D=64][K=512], 64x64 tiles via LDS
__global__ void vtrans_kernel(const u16* __restrict__ v16, u16* __restrict__ vt16) {
  __shared__ u16 tile[64 * 72];
  int kt = blockIdx.x;   // 0..7
  int bh = blockIdx.y;   // 0..511
  int t = threadIdx.x;   // 256
  const u16* src = v16 + ((size_t)bh * 512 + kt * 64) * 64;
  #pragma unroll
  for (int j = 0; j < 2; j++) {
    int linear = j * 2048 + t * 8;
    int kr = linear >> 6, d0 = linear & 63;
    bf16x8 vv = *(const bf16x8*)(src + (size_t)kr * 64 + d0);
    #pragma unroll
    for (int e = 0; e < 8; e++) tile[kr * 72 + d0 + e] = (u16)vv[e];
  }
  __syncthreads();
  #pragma unroll
  for (int j = 0; j < 2; j++) {
    int linear = j * 2048 + t * 8;
    int dr = linear >> 6, k0 = linear & 63;
    bf16x8 ov;
    #pragma unroll
    for (int e = 0; e < 8; e++) ov[e] = (short)tile[(k0 + e) * 72 + dr];
    *(bf16x8*)(vt16 + ((size_t)bh * 64 + dr) * 512 + kt * 64 + k0) = ov;
  }
}

// ---------------------------------------------------------------- fused attention
// One block per (q-tile of 64 rows, h, b). 4 waves; wave w owns q rows
// [qt*64 + w*16, +16). S (16x512 per wave) lives in 32 f32x4 accumulators.
// Softmax reduced with 16-lane shuffles (rows live in one 16-lane group).
// P (unnormalized exp) goes through padded LDS to reach MFMA A-layout;
// O is rescaled by 1/rowsum at the epilogue.
__global__ __launch_bounds__(256, 2)
void attn_kernel(const u16* __restrict__ q16, const u16* __restrict__ k16,
                 const u16* __restrict__ vt16, const float* __restrict__ sim,
                 const float* __restrict__ wsim, u16* __restrict__ attn16) {
  __shared__ u16 Plds[64 * 520];   // 520 = 512 + 8 pad (keeps 16B align, kills conflicts)
  int qt = blockIdx.x, h = blockIdx.y, b = blockIdx.z;
  int bh = b * NH + h;
  int tid = threadIdx.x;
  int wave = tid >> 6, lane = tid & 63;
  int lr = lane & 15, qd = lane >> 4;
  int qrb = qt * 64 + wave * 16;

  const u16* qp = q16 + ((size_t)bh * 512 + qrb + lr) * 64 + qd * 8;
  bf16x8 aq0 = *(const bf16x8*)qp;
  bf16x8 aq1 = *(const bf16x8*)(qp + 32);

  f32x4 zero = {0.f, 0.f, 0.f, 0.f};
  f32x4 s[32];
  #pragma unroll
  for (int jt = 0; jt < 32; jt++) {
    const u16* kp = k16 + ((size_t)bh * 512 + jt * 16 + lr) * 64 + qd * 8;
    f32x4 t = zero;
    t = __builtin_amdgcn_mfma_f32_16x16x32_bf16(aq0, *(const bf16x8*)kp, t, 0, 0, 0);
    t = __builtin_amdgcn_mfma_f32_16x16x32_bf16(aq1, *(const bf16x8*)(kp + 32), t, 0, 0, 0);
    s[jt] = t;
  }

  float ws = wsim[h];
  int row0 = qrb + qd * 4;    // global q row for reg r: row0 + r
  #pragma unroll
  for (int jt = 0; jt < 32; jt++)
    #pragma unroll
    for (int r = 0; r < 4; r++)
      s[jt][r] += ws * sim[(size_t)(row0 + r) * 512 + jt * 16 + lr];

  float mx[4];
  #pragma unroll
  for (int r = 0; r < 4; r++) {
    float m = s[0][r];
    #pragma unroll
    for (int jt = 1; jt < 32; jt++) m = fmaxf(m, s[jt][r]);
    m = fmaxf(m, __shfl_xor(m, 1));
    m = fmaxf(m, __shfl_xor(m, 2));
    m = fmaxf(m, __shfl_xor(m, 4));
    m = fmaxf(m, __shfl_xor(m, 8));
    mx[r] = m;
  }
  float sum[4] = {0.f, 0.f, 0.f, 0.f};
  #pragma unroll
  for (int jt = 0; jt < 32; jt++)
    #pragma unroll
    for (int r = 0; r < 4; r++) {
      float e = __expf(s[jt][r] - mx[r]);
      s[jt][r] = e;
      sum[r] += e;
    }
  float inv[4];
  #pragma unroll
  for (int r = 0; r < 4; r++) {
    float t = sum[r];
    t += __shfl_xor(t, 1); t += __shfl_xor(t, 2);
    t += __shfl_xor(t, 4); t += __shfl_xor(t, 8);
    inv[r] = 1.0f / t;
  }
  #pragma unroll
  for (int jt = 0; jt < 32; jt++)
    #pragma unroll
    for (int r = 0; r < 4; r++)
      Plds[(wave * 16 + qd * 4 + r) * 520 + jt * 16 + lr] = f2bf(s[jt][r]);
  __syncthreads();

  f32x4 o[4];
  #pragma unroll
  for (int nt = 0; nt < 4; nt++) o[nt] = zero;
  #pragma unroll
  for (int ks = 0; ks < 16; ks++) {
    bf16x8 ap = *(const bf16x8*)&Plds[(wave * 16 + lr) * 520 + ks * 32 + qd * 8];
    #pragma unroll
    for (int nt = 0; nt < 4; nt++) {
      const u16* vp = vt16 + ((size_t)bh * 64 + nt * 16 + lr) * 512 + ks * 32 + qd * 8;
      o[nt] = __builtin_amdgcn_mfma_f32_16x16x32_bf16(ap, *(const bf16x8*)vp, o[nt], 0, 0, 0);
    }
  }
  #pragma unroll
  for (int nt = 0; nt < 4; nt++)
    #pragma unroll
    for (int r = 0; r < 4; r++) {
      float val = o[nt][r] * inv[r];
      attn16[((size_t)b * 512 + row0 + r) * 1024 + h * 64 + nt * 16 + lr] = f2bf(val);
    }
}

// ---------------------------------------------------------------- launch
extern "C" void kernel_launch(void* const* d_in, const int* in_sizes, int n_in,
                              void* d_out, int out_size, void* d_ws, size_t ws_size,
                              hipStream_t stream) {
  const float* hR  = (const float*)d_in[0];
  const float* R   = (const float*)d_in[1];
  const float* Wq  = (const float*)d_in[2];
  const float* Wk  = (const float*)d_in[3];
  const float* Wv  = (const float*)d_in[4];
  const float* Wo  = (const float*)d_in[5];
  const float* wsm = (const float*)d_in[6];
  float* out = (float*)d_out;

  const size_t NE = 16777216;   // 16384 x 1024
  u16* ws16   = (u16*)d_ws;
  u16* hR16   = ws16;           // reused as attn16 after QKV GEMM consumes hR16
  u16* attn16 = ws16;
  u16* q16    = ws16 + NE;
  u16* k16    = ws16 + 2 * NE;
  u16* v16    = ws16 + 3 * NE;
  u16* vt16   = ws16 + 4 * NE;
  u16* Wq16   = ws16 + 5 * NE;
  u16* Wk16   = Wq16 + 1048576;
  u16* Wv16   = Wk16 + 1048576;
  u16* Wo16   = Wv16 + 1048576;
  float* Rn   = (float*)(Wo16 + 1048576);
  float* sim  = Rn + 512 * 256;
  // total ws use: 5*NE*2 + 4*1M*2 + (131072+262144)*4 bytes ~= 178 MB

  convert_kernel<<<20480, 256, 0, stream>>>(hR, Wq, Wk, Wv, Wo,
                                            hR16, Wq16, Wk16, Wv16, Wo16);
  rnorm_kernel<<<512, 64, 0, stream>>>(R, Rn);
  sim_kernel<<<32, 256, 0, stream>>>(Rn, sim);
  gemm_kernel<0><<<dim3(128, 24), 256, 0, stream>>>(hR16, Wq16, Wk16, Wv16,
                                                    q16, k16, v16, nullptr);
  vtrans_kernel<<<dim3(8, 512), 256, 0, stream>>>(v16, vt16);
  attn_kernel<<<dim3(8, 16, 32), 256, 0, stream>>>(q16, k16, vt16, sim, wsm, attn16);
  gemm_kernel<1><<<dim3(128, 8), 256, 0, stream>>>(attn16, Wo16, nullptr, nullptr,
                                                   nullptr, nullptr, nullptr, out);
}